// Round 9
// baseline (170.756 us; speedup 1.0000x reference)
//
#include <hip/hip_runtime.h>

#define NN 4096
#define DD 512
#define TT 4096

typedef __bf16 bf16x8 __attribute__((ext_vector_type(8)));
typedef float f32x4 __attribute__((ext_vector_type(4)));

constexpr float INV_TEMP = 1.0f / 0.07f;

#define AS1(p) ((__attribute__((address_space(1))) const void*)(p))
#define AS3(p) ((__attribute__((address_space(3))) void*)(p))

// ---------------- normalize: fp32 -> normalized bf16; zero tail counter ----------------
__global__ __launch_bounds__(256) void k_normalize(const float* __restrict__ emb,
                                                   __bf16* __restrict__ nemb,
                                                   int* __restrict__ counter) {
    if (blockIdx.x == 0 && threadIdx.x == 0) *counter = 0;
    int wave = threadIdx.x >> 6, lane = threadIdx.x & 63;
    int row = blockIdx.x * 4 + wave;
    const float4* src = (const float4*)(emb + (size_t)row * DD);
    float4 x0 = src[lane * 2 + 0];
    float4 x1 = src[lane * 2 + 1];
    float ss = x0.x * x0.x + x0.y * x0.y + x0.z * x0.z + x0.w * x0.w +
               x1.x * x1.x + x1.y * x1.y + x1.z * x1.z + x1.w * x1.w;
    #pragma unroll
    for (int m = 1; m < 64; m <<= 1) ss += __shfl_xor(ss, m, 64);
    float inv = 1.0f / fmaxf(sqrtf(ss), 1e-8f);
    bf16x8 v;
    v[0] = (__bf16)(x0.x * inv); v[1] = (__bf16)(x0.y * inv);
    v[2] = (__bf16)(x0.z * inv); v[3] = (__bf16)(x0.w * inv);
    v[4] = (__bf16)(x1.x * inv); v[5] = (__bf16)(x1.y * inv);
    v[6] = (__bf16)(x1.z * inv); v[7] = (__bf16)(x1.w * inv);
    *(bf16x8*)(nemb + (size_t)row * DD + lane * 8) = v;
}

// ---------------- fused contrastive (blocks 0..1023) + triplet (blocks 1024..2047) ----------------
// Contrast: full 32x32 tile grid, 128x128 tile, BK=64, single-buffer global_load_lds.
// Triplet blocks (no LDS) co-schedule with LDS-limited contrast blocks and fill stalls.
__global__ __launch_bounds__(256) void k_conttrip(const __bf16* __restrict__ nemb,
                                                  const int* __restrict__ labels,
                                                  const float* __restrict__ emb,
                                                  const int* __restrict__ trip,
                                                  float* __restrict__ posP,
                                                  float* __restrict__ totP,
                                                  float* __restrict__ cntP,
                                                  float* __restrict__ tl) {
    int tid = threadIdx.x;
    int lane = tid & 63, wave = tid >> 6;

    if (blockIdx.x >= 1024) {
        // ---- triplet path: 4 triplets per block, one per wave ----
        int t = (blockIdx.x - 1024) * 4 + wave;
        int ia = trip[t * 3 + 0], ip = trip[t * 3 + 1], ig = trip[t * 3 + 2];
        const float4* pa = (const float4*)(emb + (size_t)ia * DD);
        const float4* pp = (const float4*)(emb + (size_t)ip * DD);
        const float4* pn = (const float4*)(emb + (size_t)ig * DD);
        float d1 = 0.0f, d2 = 0.0f;
        #pragma unroll
        for (int j = 0; j < 2; ++j) {
            float4 a = pa[lane * 2 + j];
            float4 p = pp[lane * 2 + j];
            float4 n = pn[lane * 2 + j];
            float dx;
            dx = a.x - p.x + 1e-6f; d1 += dx * dx;
            dx = a.y - p.y + 1e-6f; d1 += dx * dx;
            dx = a.z - p.z + 1e-6f; d1 += dx * dx;
            dx = a.w - p.w + 1e-6f; d1 += dx * dx;
            dx = a.x - n.x + 1e-6f; d2 += dx * dx;
            dx = a.y - n.y + 1e-6f; d2 += dx * dx;
            dx = a.z - n.z + 1e-6f; d2 += dx * dx;
            dx = a.w - n.w + 1e-6f; d2 += dx * dx;
        }
        #pragma unroll
        for (int m = 1; m < 64; m <<= 1) {
            d1 += __shfl_xor(d1, m, 64);
            d2 += __shfl_xor(d2, m, 64);
        }
        if (lane == 0) tl[t] = fmaxf(sqrtf(d1) - sqrtf(d2) + 0.5f, 0.0f);
        return;
    }

    // ---- contrast path ----
    __shared__ __attribute__((aligned(16))) __bf16 aSm[128 * 64];
    __shared__ __attribute__((aligned(16))) __bf16 bSm[128 * 64];
    __shared__ int rlab[128];
    __shared__ int clab[128];

    int wr = wave >> 1, wc = wave & 1;
    int l15 = lane & 15, quad = lane >> 4;
    int rowblk = blockIdx.x >> 5, colblk = blockIdx.x & 31;
    int row0 = rowblk * 128, col0 = colblk * 128;

    if (tid < 128) rlab[tid] = labels[row0 + tid];
    else           clab[tid - 128] = labels[col0 + tid - 128];

    f32x4 acc[4][4];
    #pragma unroll
    for (int r = 0; r < 4; ++r)
        #pragma unroll
        for (int c = 0; c < 4; ++c) {
            f32x4 z = {0.0f, 0.0f, 0.0f, 0.0f};
            acc[r][c] = z;
        }

    // staging: 128 rows x 64 cols per panel; thread covers (tid>>3 + 32*op, chunk tid&7)
    // LDS elem offset = op*2048 + tid*8  (contiguous lane*16B per op — global_load_lds layout)
    const __bf16* gA = nemb + (size_t)(row0 + (tid >> 3)) * DD + (tid & 7) * 8;
    const __bf16* gB = nemb + (size_t)(col0 + (tid >> 3)) * DD + (tid & 7) * 8;

    for (int kt = 0; kt < 8; ++kt) {
        int kb = kt * 64;
        __syncthreads();   // all waves done reading previous tile
        #pragma unroll
        for (int op = 0; op < 4; ++op) {
            __builtin_amdgcn_global_load_lds(AS1(gA + (size_t)(32 * op) * DD + kb),
                                             AS3(aSm + op * 2048 + tid * 8), 16, 0, 0);
            __builtin_amdgcn_global_load_lds(AS1(gB + (size_t)(32 * op) * DD + kb),
                                             AS3(bSm + op * 2048 + tid * 8), 16, 0, 0);
        }
        __syncthreads();   // vmcnt(0) drain: tile resident

        #pragma unroll
        for (int kc = 0; kc < 2; ++kc) {
            bf16x8 af[4], bfr[4];
            #pragma unroll
            for (int r = 0; r < 4; ++r)
                af[r] = *(const bf16x8*)(aSm + (wr * 64 + r * 16 + l15) * 64 + kc * 32 + quad * 8);
            #pragma unroll
            for (int c = 0; c < 4; ++c)
                bfr[c] = *(const bf16x8*)(bSm + (wc * 64 + c * 16 + l15) * 64 + kc * 32 + quad * 8);
            #pragma unroll
            for (int r = 0; r < 4; ++r)
                #pragma unroll
                for (int c = 0; c < 4; ++c)
                    acc[r][c] = __builtin_amdgcn_mfma_f32_16x16x32_bf16(af[r], bfr[c], acc[r][c], 0, 0, 0);
        }
    }

    // epilogue: exp, mask, row partial sums (slot = colblk*2 + wc; all 64 slots/row written)
    int cl[4];
    #pragma unroll
    for (int c = 0; c < 4; ++c) cl[c] = clab[wc * 64 + c * 16 + l15];

    #pragma unroll
    for (int r = 0; r < 4; ++r) {
        float tv[4] = {0, 0, 0, 0}, pv[4] = {0, 0, 0, 0}, cv[4] = {0, 0, 0, 0};
        int gibase = row0 + wr * 64 + r * 16 + quad * 4;
        int rl[4];
        #pragma unroll
        for (int v = 0; v < 4; ++v) rl[v] = rlab[wr * 64 + r * 16 + quad * 4 + v];
        #pragma unroll
        for (int c = 0; c < 4; ++c) {
            int gj = col0 + wc * 64 + c * 16 + l15;
            #pragma unroll
            for (int v = 0; v < 4; ++v) {
                float e = __expf(acc[r][c][v] * INV_TEMP);
                tv[v] += e;
                bool match = (rl[v] == cl[c]) && ((gibase + v) != gj);
                pv[v] += match ? e : 0.0f;
                cv[v] += match ? 1.0f : 0.0f;
            }
        }
        #pragma unroll
        for (int m = 1; m < 16; m <<= 1) {
            #pragma unroll
            for (int v = 0; v < 4; ++v) {
                tv[v] += __shfl_xor(tv[v], m, 64);
                pv[v] += __shfl_xor(pv[v], m, 64);
                cv[v] += __shfl_xor(cv[v], m, 64);
            }
        }
        if (l15 == 0) {
            #pragma unroll
            for (int v = 0; v < 4; ++v) {
                int gr = gibase + v;
                int oidx = gr * 64 + colblk * 2 + wc;
                posP[oidx] = pv[v];
                totP[oidx] = tv[v];
                cntP[oidx] = cv[v];
            }
        }
    }
}

// ---------------- fused tail: rowloss (all blocks) + final (last-finishing block) ----------------
__global__ __launch_bounds__(256) void k_tail(const float* __restrict__ posP,
                                              const float* __restrict__ totP,
                                              const float* __restrict__ cntP,
                                              const float* __restrict__ tl,
                                              float* __restrict__ rloss,
                                              float* __restrict__ rvalid,
                                              int* __restrict__ counter,
                                              float* __restrict__ out) {
    int tid = threadIdx.x;
    int wave = tid >> 6, lane = tid & 63;
    int row = blockIdx.x * 4 + wave;
    float p = posP[row * 64 + lane];
    float t = totP[row * 64 + lane];
    float c = cntP[row * 64 + lane];
    #pragma unroll
    for (int m = 1; m < 64; m <<= 1) {
        p += __shfl_xor(p, m, 64);
        t += __shfl_xor(t, m, 64);
        c += __shfl_xor(c, m, 64);
    }
    if (lane == 0) {
        float loss = -logf(p / (t + 1e-8f) + 1e-8f);
        bool valid = c > 0.0f;
        rloss[row] = valid ? loss : 0.0f;
        rvalid[row] = valid ? 1.0f : 0.0f;
    }

    // last-finishing block performs the final reduction (threadFenceReduction pattern)
    __shared__ int isLast;
    __threadfence();          // all threads: order rloss/rvalid writes device-wide
    __syncthreads();
    if (tid == 0) {
        int old = atomicAdd(counter, 1);
        isLast = (old == (int)gridDim.x - 1) ? 1 : 0;
    }
    __syncthreads();
    if (isLast) {
        float sl = 0.0f, sv = 0.0f, st = 0.0f;
        for (int i = tid; i < NN; i += 256) {
            sl += rloss[i];
            sv += rvalid[i];
            st += tl[i];
        }
        #pragma unroll
        for (int m = 1; m < 64; m <<= 1) {
            sl += __shfl_xor(sl, m, 64);
            sv += __shfl_xor(sv, m, 64);
            st += __shfl_xor(st, m, 64);
        }
        __shared__ float red[3][4];
        if (lane == 0) { red[0][wave] = sl; red[1][wave] = sv; red[2][wave] = st; }
        __syncthreads();
        if (tid == 0) {
            float SL = red[0][0] + red[0][1] + red[0][2] + red[0][3];
            float SV = red[1][0] + red[1][1] + red[1][2] + red[1][3];
            float ST = red[2][0] + red[2][1] + red[2][2] + red[2][3];
            float cont = (SV > 0.0f) ? (SL / SV) : 0.0f;
            float trip = ST * (1.0f / (float)TT);
            out[0] = cont + 0.3f * trip;
            out[1] = cont;
            out[2] = trip;
        }
    }
}

extern "C" void kernel_launch(void* const* d_in, const int* in_sizes, int n_in,
                              void* d_out, int out_size, void* d_ws, size_t ws_size,
                              hipStream_t stream) {
    const float* emb = (const float*)d_in[0];
    const int* labels = (const int*)d_in[1];
    const int* trips = (const int*)d_in[2];
    float* out = (float*)d_out;
    char* ws = (char*)d_ws;

    __bf16* nemb  = (__bf16*)(ws);                 // 4096*512*2 = 4194304 B
    float* posP   = (float*)(ws + 4194304);        // 4096*64*4  = 1048576 B
    float* totP   = (float*)(ws + 5242880);        // 1048576 B
    float* cntP   = (float*)(ws + 6291456);        // 1048576 B
    float* rloss  = (float*)(ws + 7340032);        // 16384 B
    float* rvalid = (float*)(ws + 7356416);        // 16384 B
    float* tl     = (float*)(ws + 7372800);        // 16384 B
    int*   counter= (int*)(ws + 7389184);          // 4 B

    k_normalize<<<NN / 4, 256, 0, stream>>>(emb, nemb, counter);
    k_conttrip<<<2048, 256, 0, stream>>>(nemb, labels, emb, trips, posP, totP, cntP, tl);
    k_tail<<<NN / 4, 256, 0, stream>>>(posP, totP, cntP, tl, rloss, rvalid, counter, out);
}

// Round 10
// 108.082 us; speedup vs baseline: 1.5799x; 1.5799x over previous
//
#include <hip/hip_runtime.h>

#define NN 4096
#define DD 512
#define TT 4096

typedef __bf16 bf16x8 __attribute__((ext_vector_type(8)));
typedef float f32x4 __attribute__((ext_vector_type(4)));

constexpr float INV_TEMP = 1.0f / 0.07f;

#define AS1(p) ((__attribute__((address_space(1))) const void*)(p))
#define AS3(p) ((__attribute__((address_space(3))) void*)(p))

// ---------------- normalize: fp32 -> normalized bf16 ----------------
__global__ __launch_bounds__(256) void k_normalize(const float* __restrict__ emb,
                                                   __bf16* __restrict__ nemb) {
    int wave = threadIdx.x >> 6, lane = threadIdx.x & 63;
    int row = blockIdx.x * 4 + wave;
    const float4* src = (const float4*)(emb + (size_t)row * DD);
    float4 x0 = src[lane * 2 + 0];
    float4 x1 = src[lane * 2 + 1];
    float ss = x0.x * x0.x + x0.y * x0.y + x0.z * x0.z + x0.w * x0.w +
               x1.x * x1.x + x1.y * x1.y + x1.z * x1.z + x1.w * x1.w;
    #pragma unroll
    for (int m = 1; m < 64; m <<= 1) ss += __shfl_xor(ss, m, 64);
    float inv = 1.0f / fmaxf(sqrtf(ss), 1e-8f);
    bf16x8 v;
    v[0] = (__bf16)(x0.x * inv); v[1] = (__bf16)(x0.y * inv);
    v[2] = (__bf16)(x0.z * inv); v[3] = (__bf16)(x0.w * inv);
    v[4] = (__bf16)(x1.x * inv); v[5] = (__bf16)(x1.y * inv);
    v[6] = (__bf16)(x1.z * inv); v[7] = (__bf16)(x1.w * inv);
    *(bf16x8*)(nemb + (size_t)row * DD + lane * 8) = v;
}

// ---------------- fused contrastive (blocks 0..1023) + triplet (blocks 1024..2047) ----------------
// Contrast: full 32x32 tile grid, 128x128 tile, BK=64, single-buffer global_load_lds.
// Triplet blocks (no LDS) co-schedule with LDS-limited contrast blocks and fill stalls.
__global__ __launch_bounds__(256) void k_conttrip(const __bf16* __restrict__ nemb,
                                                  const int* __restrict__ labels,
                                                  const float* __restrict__ emb,
                                                  const int* __restrict__ trip,
                                                  float* __restrict__ posP,
                                                  float* __restrict__ totP,
                                                  float* __restrict__ cntP,
                                                  float* __restrict__ tl) {
    int tid = threadIdx.x;
    int lane = tid & 63, wave = tid >> 6;

    if (blockIdx.x >= 1024) {
        // ---- triplet path: 4 triplets per block, one per wave ----
        int t = (blockIdx.x - 1024) * 4 + wave;
        int ia = trip[t * 3 + 0], ip = trip[t * 3 + 1], ig = trip[t * 3 + 2];
        const float4* pa = (const float4*)(emb + (size_t)ia * DD);
        const float4* pp = (const float4*)(emb + (size_t)ip * DD);
        const float4* pn = (const float4*)(emb + (size_t)ig * DD);
        float d1 = 0.0f, d2 = 0.0f;
        #pragma unroll
        for (int j = 0; j < 2; ++j) {
            float4 a = pa[lane * 2 + j];
            float4 p = pp[lane * 2 + j];
            float4 n = pn[lane * 2 + j];
            float dx;
            dx = a.x - p.x + 1e-6f; d1 += dx * dx;
            dx = a.y - p.y + 1e-6f; d1 += dx * dx;
            dx = a.z - p.z + 1e-6f; d1 += dx * dx;
            dx = a.w - p.w + 1e-6f; d1 += dx * dx;
            dx = a.x - n.x + 1e-6f; d2 += dx * dx;
            dx = a.y - n.y + 1e-6f; d2 += dx * dx;
            dx = a.z - n.z + 1e-6f; d2 += dx * dx;
            dx = a.w - n.w + 1e-6f; d2 += dx * dx;
        }
        #pragma unroll
        for (int m = 1; m < 64; m <<= 1) {
            d1 += __shfl_xor(d1, m, 64);
            d2 += __shfl_xor(d2, m, 64);
        }
        if (lane == 0) tl[t] = fmaxf(sqrtf(d1) - sqrtf(d2) + 0.5f, 0.0f);
        return;
    }

    // ---- contrast path ----
    __shared__ __attribute__((aligned(16))) __bf16 aSm[128 * 64];
    __shared__ __attribute__((aligned(16))) __bf16 bSm[128 * 64];
    __shared__ int rlab[128];
    __shared__ int clab[128];

    int wr = wave >> 1, wc = wave & 1;
    int l15 = lane & 15, quad = lane >> 4;
    int rowblk = blockIdx.x >> 5, colblk = blockIdx.x & 31;
    int row0 = rowblk * 128, col0 = colblk * 128;

    if (tid < 128) rlab[tid] = labels[row0 + tid];
    else           clab[tid - 128] = labels[col0 + tid - 128];

    f32x4 acc[4][4];
    #pragma unroll
    for (int r = 0; r < 4; ++r)
        #pragma unroll
        for (int c = 0; c < 4; ++c) {
            f32x4 z = {0.0f, 0.0f, 0.0f, 0.0f};
            acc[r][c] = z;
        }

    // staging: 128 rows x 64 cols per panel; thread covers (tid>>3 + 32*op, chunk tid&7)
    // LDS elem offset = op*2048 + tid*8  (contiguous lane*16B per op — global_load_lds layout)
    const __bf16* gA = nemb + (size_t)(row0 + (tid >> 3)) * DD + (tid & 7) * 8;
    const __bf16* gB = nemb + (size_t)(col0 + (tid >> 3)) * DD + (tid & 7) * 8;

    for (int kt = 0; kt < 8; ++kt) {
        int kb = kt * 64;
        __syncthreads();   // all waves done reading previous tile
        #pragma unroll
        for (int op = 0; op < 4; ++op) {
            __builtin_amdgcn_global_load_lds(AS1(gA + (size_t)(32 * op) * DD + kb),
                                             AS3(aSm + op * 2048 + tid * 8), 16, 0, 0);
            __builtin_amdgcn_global_load_lds(AS1(gB + (size_t)(32 * op) * DD + kb),
                                             AS3(bSm + op * 2048 + tid * 8), 16, 0, 0);
        }
        __syncthreads();   // vmcnt(0) drain: tile resident

        #pragma unroll
        for (int kc = 0; kc < 2; ++kc) {
            bf16x8 af[4], bfr[4];
            #pragma unroll
            for (int r = 0; r < 4; ++r)
                af[r] = *(const bf16x8*)(aSm + (wr * 64 + r * 16 + l15) * 64 + kc * 32 + quad * 8);
            #pragma unroll
            for (int c = 0; c < 4; ++c)
                bfr[c] = *(const bf16x8*)(bSm + (wc * 64 + c * 16 + l15) * 64 + kc * 32 + quad * 8);
            #pragma unroll
            for (int r = 0; r < 4; ++r)
                #pragma unroll
                for (int c = 0; c < 4; ++c)
                    acc[r][c] = __builtin_amdgcn_mfma_f32_16x16x32_bf16(af[r], bfr[c], acc[r][c], 0, 0, 0);
        }
    }

    // epilogue: exp, mask, row partial sums (slot = colblk*2 + wc; all 64 slots/row written)
    int cl[4];
    #pragma unroll
    for (int c = 0; c < 4; ++c) cl[c] = clab[wc * 64 + c * 16 + l15];

    #pragma unroll
    for (int r = 0; r < 4; ++r) {
        float tv[4] = {0, 0, 0, 0}, pv[4] = {0, 0, 0, 0}, cv[4] = {0, 0, 0, 0};
        int gibase = row0 + wr * 64 + r * 16 + quad * 4;
        int rl[4];
        #pragma unroll
        for (int v = 0; v < 4; ++v) rl[v] = rlab[wr * 64 + r * 16 + quad * 4 + v];
        #pragma unroll
        for (int c = 0; c < 4; ++c) {
            int gj = col0 + wc * 64 + c * 16 + l15;
            #pragma unroll
            for (int v = 0; v < 4; ++v) {
                float e = __expf(acc[r][c][v] * INV_TEMP);
                tv[v] += e;
                bool match = (rl[v] == cl[c]) && ((gibase + v) != gj);
                pv[v] += match ? e : 0.0f;
                cv[v] += match ? 1.0f : 0.0f;
            }
        }
        #pragma unroll
        for (int m = 1; m < 16; m <<= 1) {
            #pragma unroll
            for (int v = 0; v < 4; ++v) {
                tv[v] += __shfl_xor(tv[v], m, 64);
                pv[v] += __shfl_xor(pv[v], m, 64);
                cv[v] += __shfl_xor(cv[v], m, 64);
            }
        }
        if (l15 == 0) {
            #pragma unroll
            for (int v = 0; v < 4; ++v) {
                int gr = gibase + v;
                int oidx = gr * 64 + colblk * 2 + wc;
                posP[oidx] = pv[v];
                totP[oidx] = tv[v];
                cntP[oidx] = cv[v];
            }
        }
    }
}

// ---------------- per-row loss: wave per row, coalesced ----------------
__global__ __launch_bounds__(256) void k_rowloss(const float* __restrict__ posP,
                                                 const float* __restrict__ totP,
                                                 const float* __restrict__ cntP,
                                                 float* __restrict__ rloss,
                                                 float* __restrict__ rvalid) {
    int wave = threadIdx.x >> 6, lane = threadIdx.x & 63;
    int row = blockIdx.x * 4 + wave;
    float p = posP[row * 64 + lane];
    float t = totP[row * 64 + lane];
    float c = cntP[row * 64 + lane];
    #pragma unroll
    for (int m = 1; m < 64; m <<= 1) {
        p += __shfl_xor(p, m, 64);
        t += __shfl_xor(t, m, 64);
        c += __shfl_xor(c, m, 64);
    }
    if (lane == 0) {
        float loss = -logf(p / (t + 1e-8f) + 1e-8f);
        bool valid = c > 0.0f;
        rloss[row] = valid ? loss : 0.0f;
        rvalid[row] = valid ? 1.0f : 0.0f;
    }
}

// ---------------- final reduction ----------------
__global__ __launch_bounds__(256) void k_final(const float* __restrict__ rloss,
                                               const float* __restrict__ rvalid,
                                               const float* __restrict__ tl,
                                               float* __restrict__ out) {
    int tid = threadIdx.x;
    float sl = 0.0f, sv = 0.0f, st = 0.0f;
    for (int i = tid; i < NN; i += 256) {
        sl += rloss[i];
        sv += rvalid[i];
        st += tl[i];
    }
    #pragma unroll
    for (int m = 1; m < 64; m <<= 1) {
        sl += __shfl_xor(sl, m, 64);
        sv += __shfl_xor(sv, m, 64);
        st += __shfl_xor(st, m, 64);
    }
    __shared__ float red[3][4];
    int lane = tid & 63, wave = tid >> 6;
    if (lane == 0) { red[0][wave] = sl; red[1][wave] = sv; red[2][wave] = st; }
    __syncthreads();
    if (tid == 0) {
        float SL = red[0][0] + red[0][1] + red[0][2] + red[0][3];
        float SV = red[1][0] + red[1][1] + red[1][2] + red[1][3];
        float ST = red[2][0] + red[2][1] + red[2][2] + red[2][3];
        float cont = (SV > 0.0f) ? (SL / SV) : 0.0f;
        float trip = ST * (1.0f / (float)TT);
        out[0] = cont + 0.3f * trip;
        out[1] = cont;
        out[2] = trip;
    }
}

extern "C" void kernel_launch(void* const* d_in, const int* in_sizes, int n_in,
                              void* d_out, int out_size, void* d_ws, size_t ws_size,
                              hipStream_t stream) {
    const float* emb = (const float*)d_in[0];
    const int* labels = (const int*)d_in[1];
    const int* trips = (const int*)d_in[2];
    float* out = (float*)d_out;
    char* ws = (char*)d_ws;

    __bf16* nemb  = (__bf16*)(ws);                 // 4096*512*2 = 4194304 B
    float* posP   = (float*)(ws + 4194304);        // 4096*64*4  = 1048576 B
    float* totP   = (float*)(ws + 5242880);        // 1048576 B
    float* cntP   = (float*)(ws + 6291456);        // 1048576 B
    float* rloss  = (float*)(ws + 7340032);        // 16384 B
    float* rvalid = (float*)(ws + 7356416);        // 16384 B
    float* tl     = (float*)(ws + 7372800);        // 16384 B

    k_normalize<<<NN / 4, 256, 0, stream>>>(emb, nemb);
    k_conttrip<<<2048, 256, 0, stream>>>(nemb, labels, emb, trips, posP, totP, cntP, tl);
    k_rowloss<<<NN / 4, 256, 0, stream>>>(posP, totP, cntP, rloss, rvalid);
    k_final<<<1, 256, 0, stream>>>(rloss, rvalid, tl, out);
}